// Round 1
// baseline (51.636 us; speedup 1.0000x reference)
//
#include <hip/hip_runtime.h>
#include <hip/hip_bf16.h>

#define NX_ 128
#define NY_ 128
#define NZ_ 16
#define NPT (NX_ * NY_ * NZ_)   // 262144
#define H_ 32
#define W_ 88
#define C_ 80
#define HW_ (H_ * W_)

__global__ __launch_bounds__(256) void fvt_kernel(
    const float* __restrict__ feat,    // (B, C, H, W)
    const float* __restrict__ intrin,  // (B, 1, 4, 4)
    const float* __restrict__ extrin,  // (B, 1, 4, 4)
    const float* __restrict__ bda,     // (B, 4, 4)
    float* __restrict__ out)           // (B, C, NX, NY, NZ)
{
    const int b = blockIdx.y;
    const int n = blockIdx.x * blockDim.x + threadIdx.x;
    if (n >= NPT) return;

    const float* In = intrin + b * 16;
    const float* Ex = extrin + b * 16;
    const float* Bd = bda    + b * 16;

    // intrinsic = intrin[:3,:3] * diag-ish row scale (rows 0,1 by 1/8)
    float K[3][3];
#pragma unroll
    for (int r = 0; r < 3; ++r)
#pragma unroll
        for (int c = 0; c < 3; ++c)
            K[r][c] = In[r * 4 + c] * (r == 2 ? 1.0f : 0.125f);

    // proj = K @ extrin[:3,:4]
    float P[3][4];
#pragma unroll
    for (int r = 0; r < 3; ++r)
#pragma unroll
        for (int c = 0; c < 4; ++c)
            P[r][c] = K[r][0] * Ex[0 * 4 + c] + K[r][1] * Ex[1 * 4 + c] + K[r][2] * Ex[2 * 4 + c];

    // M = proj @ bda  (3x4)
    float M[3][4];
#pragma unroll
    for (int r = 0; r < 3; ++r)
#pragma unroll
        for (int c = 0; c < 4; ++c)
            M[r][c] = P[r][0] * Bd[0 * 4 + c] + P[r][1] * Bd[1 * 4 + c]
                    + P[r][2] * Bd[2 * 4 + c] + P[r][3] * Bd[3 * 4 + c];

    // frustum point for this n: n = ix*NY*NZ + iy*NZ + iz
    const int iz = n & (NZ_ - 1);
    const int iy = (n >> 4) & (NY_ - 1);
    const int ix = n >> 11;
    const float xf = -51.2f + (float)ix * 0.8f;
    const float yf = -51.2f + (float)iy * 0.8f;
    const float zf = -5.0f  + (float)iz * 0.5f;

    const float px = M[0][0] * xf + M[0][1] * yf + M[0][2] * zf + M[0][3];
    const float py = M[1][0] * xf + M[1][1] * yf + M[1][2] * zf + M[1][3];
    const float pz = M[2][0] * xf + M[2][1] * yf + M[2][2] * zf + M[2][3];

    float u = px / pz;
    float v = py / pz;
    u = u / (float)W_ * 2.0f - 1.0f;
    v = v / (float)H_ * 2.0f - 1.0f;

    // grid_sample coords
    float x = (u + 1.0f) * 0.5f * (float)(W_ - 1);
    float y = (v + 1.0f) * 0.5f * (float)(H_ - 1);
    const bool fin = __builtin_isfinite(x) && __builtin_isfinite(y);
    x = fin ? x : -10.0f;
    y = fin ? y : -10.0f;

    const float x0 = floorf(x);
    const float y0 = floorf(y);
    const float x1 = x0 + 1.0f;
    const float y1 = y0 + 1.0f;
    const float wx1 = x - x0, wx0 = 1.0f - wx1;
    const float wy1 = y - y0, wy0 = 1.0f - wy1;

    int   idx[4];
    float wgt[4];
    const float cx[4] = {x0, x1, x0, x1};
    const float cy[4] = {y0, y0, y1, y1};
    const float cw[4] = {wx0 * wy0, wx1 * wy0, wx0 * wy1, wx1 * wy1};
#pragma unroll
    for (int k = 0; k < 4; ++k) {
        const bool valid = (cx[k] >= 0.0f) && (cx[k] < (float)W_) &&
                           (cy[k] >= 0.0f) && (cy[k] < (float)H_);
        const float xc = fminf(fmaxf(cx[k], 0.0f), (float)(W_ - 1));
        const float yc = fminf(fmaxf(cy[k], 0.0f), (float)(H_ - 1));
        idx[k] = (int)yc * W_ + (int)xc;
        wgt[k] = valid ? cw[k] : 0.0f;
    }

    const float* fb = feat + (size_t)b * C_ * HW_;
    float* ob = out + (size_t)b * C_ * NPT + n;

#pragma unroll 4
    for (int c = 0; c < C_; ++c) {
        const float* fp = fb + c * HW_;
        const float val = wgt[0] * fp[idx[0]] + wgt[1] * fp[idx[1]] +
                          wgt[2] * fp[idx[2]] + wgt[3] * fp[idx[3]];
        ob[(size_t)c * NPT] = val;
    }
}

extern "C" void kernel_launch(void* const* d_in, const int* in_sizes, int n_in,
                              void* d_out, int out_size, void* d_ws, size_t ws_size,
                              hipStream_t stream) {
    const float* feat   = (const float*)d_in[0];
    const float* intrin = (const float*)d_in[1];
    const float* extrin = (const float*)d_in[2];
    const float* bda    = (const float*)d_in[3];
    float* out = (float*)d_out;

    const int B = in_sizes[0] / (C_ * HW_);
    dim3 block(256);
    dim3 grid(NPT / 256, B);
    fvt_kernel<<<grid, block, 0, stream>>>(feat, intrin, extrin, bda, out);
}

// Round 2
// 43.580 us; speedup vs baseline: 1.1849x; 1.1849x over previous
//
#include <hip/hip_runtime.h>
#include <hip/hip_bf16.h>

#define NXg 128
#define NYg 128
#define NZg 16
#define NPT (NXg * NYg * NZg)   // 262144
#define Hh 32
#define Ww 88
#define Cc 80
#define HWc (Hh * Ww)
#define CSPLIT 4
#define CPB (Cc / CSPLIT)       // 20 channels per block

// feat (B,C,H,W) -> featT (B,H,W,C)
__global__ __launch_bounds__(256) void fvt_transpose(
    const float* __restrict__ feat, float* __restrict__ featT, int total)
{
    int t = blockIdx.x * 256 + threadIdx.x;
    if (t >= total) return;
    int c = t % Cc; int r = t / Cc;
    int w = r % Ww; r /= Ww;
    int h = r % Hh; int b = r / Hh;
    featT[t] = feat[((b * Cc + c) * Hh + h) * Ww + w];
}

__global__ __launch_bounds__(256) void fvt_kernel(
    const float* __restrict__ featT,   // (B, H, W, C)
    const float* __restrict__ intrin,  // (B, 1, 4, 4)
    const float* __restrict__ extrin,  // (B, 1, 4, 4)
    const float* __restrict__ bda,     // (B, 4, 4)
    float* __restrict__ out)           // (B, C, NX, NY, NZ)
{
    const int b  = blockIdx.y;
    const int cq = blockIdx.z;
    const int t  = blockIdx.x * blockDim.x + threadIdx.x;
    const int n0 = t << 2;              // 4 consecutive n (same z-column)
    if (n0 >= NPT) return;

    const float* In = intrin + b * 16;
    const float* Ex = extrin + b * 16;
    const float* Bd = bda    + b * 16;

    float K[3][3];
#pragma unroll
    for (int r = 0; r < 3; ++r)
#pragma unroll
        for (int c = 0; c < 3; ++c)
            K[r][c] = In[r * 4 + c] * (r == 2 ? 1.0f : 0.125f);

    float P[3][4];
#pragma unroll
    for (int r = 0; r < 3; ++r)
#pragma unroll
        for (int c = 0; c < 4; ++c)
            P[r][c] = K[r][0] * Ex[0 * 4 + c] + K[r][1] * Ex[1 * 4 + c] + K[r][2] * Ex[2 * 4 + c];

    float M[3][4];
#pragma unroll
    for (int r = 0; r < 3; ++r)
#pragma unroll
        for (int c = 0; c < 4; ++c)
            M[r][c] = P[r][0] * Bd[0 * 4 + c] + P[r][1] * Bd[1 * 4 + c]
                    + P[r][2] * Bd[2 * 4 + c] + P[r][3] * Bd[3 * 4 + c];

    const int iz0 = n0 & (NZg - 1);
    const int iy  = (n0 >> 4) & (NYg - 1);
    const int ix  = n0 >> 11;
    const float xf = -51.2f + (float)ix * 0.8f;
    const float yf = -51.2f + (float)iy * 0.8f;

    int   idxb[4][4];   // [j (z-step)][k (corner)] float offset into featT[b], channel 0
    float wgt [4][4];

#pragma unroll
    for (int j = 0; j < 4; ++j) {
        const float zf = -5.0f + (float)(iz0 + j) * 0.5f;

        const float px = M[0][0] * xf + M[0][1] * yf + M[0][2] * zf + M[0][3];
        const float py = M[1][0] * xf + M[1][1] * yf + M[1][2] * zf + M[1][3];
        const float pz = M[2][0] * xf + M[2][1] * yf + M[2][2] * zf + M[2][3];

        float u = px / pz;
        float v = py / pz;
        u = u / (float)Ww * 2.0f - 1.0f;
        v = v / (float)Hh * 2.0f - 1.0f;

        float x = (u + 1.0f) * 0.5f * (float)(Ww - 1);
        float y = (v + 1.0f) * 0.5f * (float)(Hh - 1);
        const bool fin = __builtin_isfinite(x) && __builtin_isfinite(y);
        x = fin ? x : -10.0f;
        y = fin ? y : -10.0f;

        const float x0 = floorf(x);
        const float y0 = floorf(y);
        const float x1 = x0 + 1.0f;
        const float y1 = y0 + 1.0f;
        const float wx1 = x - x0, wx0 = 1.0f - wx1;
        const float wy1 = y - y0, wy0 = 1.0f - wy1;

        const float cx[4] = {x0, x1, x0, x1};
        const float cy[4] = {y0, y0, y1, y1};
        const float cw[4] = {wx0 * wy0, wx1 * wy0, wx0 * wy1, wx1 * wy1};
#pragma unroll
        for (int k = 0; k < 4; ++k) {
            const bool valid = (cx[k] >= 0.0f) && (cx[k] < (float)Ww) &&
                               (cy[k] >= 0.0f) && (cy[k] < (float)Hh);
            const float xc = fminf(fmaxf(cx[k], 0.0f), (float)(Ww - 1));
            const float yc = fminf(fmaxf(cy[k], 0.0f), (float)(Hh - 1));
            idxb[j][k] = ((int)yc * Ww + (int)xc) * Cc;
            wgt [j][k] = valid ? cw[k] : 0.0f;
        }
    }

    const float* fb = featT + (size_t)b * HWc * Cc + cq * CPB;
    float* ob = out + ((size_t)b * Cc + cq * CPB) * (size_t)NPT + n0;

#pragma unroll 2
    for (int cg = 0; cg < CPB / 4; ++cg) {
        float acc[4][4];   // [cc (channel within group)][j (z-step)]
#pragma unroll
        for (int cc = 0; cc < 4; ++cc)
#pragma unroll
            for (int j = 0; j < 4; ++j) acc[cc][j] = 0.0f;

#pragma unroll
        for (int k = 0; k < 4; ++k) {
#pragma unroll
            for (int j = 0; j < 4; ++j) {
                const float4 f = *reinterpret_cast<const float4*>(fb + idxb[j][k] + (cg << 2));
                const float wk = wgt[j][k];
                acc[0][j] = fmaf(wk, f.x, acc[0][j]);
                acc[1][j] = fmaf(wk, f.y, acc[1][j]);
                acc[2][j] = fmaf(wk, f.z, acc[2][j]);
                acc[3][j] = fmaf(wk, f.w, acc[3][j]);
            }
        }
#pragma unroll
        for (int cc = 0; cc < 4; ++cc) {
            *reinterpret_cast<float4*>(ob + (size_t)(cg * 4 + cc) * NPT) =
                make_float4(acc[cc][0], acc[cc][1], acc[cc][2], acc[cc][3]);
        }
    }
}

extern "C" void kernel_launch(void* const* d_in, const int* in_sizes, int n_in,
                              void* d_out, int out_size, void* d_ws, size_t ws_size,
                              hipStream_t stream) {
    const float* feat   = (const float*)d_in[0];
    const float* intrin = (const float*)d_in[1];
    const float* extrin = (const float*)d_in[2];
    const float* bda    = (const float*)d_in[3];
    float* out   = (float*)d_out;
    float* featT = (float*)d_ws;

    const int B = in_sizes[0] / (Cc * HWc);
    const int total = B * HWc * Cc;

    fvt_transpose<<<(total + 255) / 256, 256, 0, stream>>>(feat, featT, total);

    dim3 block(256);
    dim3 grid(NPT / 4 / 256, B, CSPLIT);
    fvt_kernel<<<grid, block, 0, stream>>>(featT, intrin, extrin, bda, out);
}

// Round 3
// 43.517 us; speedup vs baseline: 1.1866x; 1.0014x over previous
//
#include <hip/hip_runtime.h>
#include <hip/hip_bf16.h>

#define NXg 128
#define NYg 128
#define NZg 16
#define NPT (NXg * NYg * NZg)   // 262144
#define Hh 32
#define Ww 88
#define Cc 80
#define HWc (Hh * Ww)
#define CSPLIT 4
#define CPB (Cc / CSPLIT)       // 20 channels per block

// feat (B,C,H,W) -> featT (B,H,W,C)
__global__ __launch_bounds__(256) void fvt_transpose(
    const float* __restrict__ feat, float* __restrict__ featT, int total)
{
    int t = blockIdx.x * 256 + threadIdx.x;
    if (t >= total) return;
    int c = t % Cc; int r = t / Cc;
    int w = r % Ww; r /= Ww;
    int h = r % Hh; int b = r / Hh;
    featT[t] = feat[((b * Cc + c) * Hh + h) * Ww + w];
}

__global__ __launch_bounds__(256) void fvt_kernel(
    const float* __restrict__ featT,   // (B, H, W, C)
    const float* __restrict__ intrin,  // (B, 1, 4, 4)
    const float* __restrict__ extrin,  // (B, 1, 4, 4)
    const float* __restrict__ bda,     // (B, 4, 4)
    float* __restrict__ out)           // (B, C, NX, NY, NZ)
{
    const int b  = blockIdx.y;
    const int cq = blockIdx.z;
    const int t  = blockIdx.x * blockDim.x + threadIdx.x;
    const int n0 = t << 2;              // 4 consecutive n (same z-column)
    if (n0 >= NPT) return;

    const float* In = intrin + b * 16;
    const float* Ex = extrin + b * 16;
    const float* Bd = bda    + b * 16;

    float K[3][3];
#pragma unroll
    for (int r = 0; r < 3; ++r)
#pragma unroll
        for (int c = 0; c < 3; ++c)
            K[r][c] = In[r * 4 + c] * (r == 2 ? 1.0f : 0.125f);

    float P[3][4];
#pragma unroll
    for (int r = 0; r < 3; ++r)
#pragma unroll
        for (int c = 0; c < 4; ++c)
            P[r][c] = K[r][0] * Ex[0 * 4 + c] + K[r][1] * Ex[1 * 4 + c] + K[r][2] * Ex[2 * 4 + c];

    float M[3][4];
#pragma unroll
    for (int r = 0; r < 3; ++r)
#pragma unroll
        for (int c = 0; c < 4; ++c)
            M[r][c] = P[r][0] * Bd[0 * 4 + c] + P[r][1] * Bd[1 * 4 + c]
                    + P[r][2] * Bd[2 * 4 + c] + P[r][3] * Bd[3 * 4 + c];

    const int iz0 = n0 & (NZg - 1);
    const int iy  = (n0 >> 4) & (NYg - 1);
    const int ix  = n0 >> 11;
    const float xf = -51.2f + (float)ix * 0.8f;
    const float yf = -51.2f + (float)iy * 0.8f;

    int   idxb[4][4];   // [j (z-step)][k (corner)] float offset into featT[b], ch 0
    float wgt [4][4];
    bool  vj  [4];
    bool  anyv = false;

#pragma unroll
    for (int j = 0; j < 4; ++j) {
        const float zf = -5.0f + (float)(iz0 + j) * 0.5f;

        const float px = M[0][0] * xf + M[0][1] * yf + M[0][2] * zf + M[0][3];
        const float py = M[1][0] * xf + M[1][1] * yf + M[1][2] * zf + M[1][3];
        const float pz = M[2][0] * xf + M[2][1] * yf + M[2][2] * zf + M[2][3];

        float u = px / pz;
        float v = py / pz;
        u = u / (float)Ww * 2.0f - 1.0f;
        v = v / (float)Hh * 2.0f - 1.0f;

        float x = (u + 1.0f) * 0.5f * (float)(Ww - 1);
        float y = (v + 1.0f) * 0.5f * (float)(Hh - 1);
        const bool fin = __builtin_isfinite(x) && __builtin_isfinite(y);
        x = fin ? x : -10.0f;
        y = fin ? y : -10.0f;

        const float x0 = floorf(x);
        const float y0 = floorf(y);
        const float x1 = x0 + 1.0f;
        const float y1 = y0 + 1.0f;
        const float wx1 = x - x0, wx0 = 1.0f - wx1;
        const float wy1 = y - y0, wy0 = 1.0f - wy1;

        const float cx[4] = {x0, x1, x0, x1};
        const float cy[4] = {y0, y0, y1, y1};
        const float cw[4] = {wx0 * wy0, wx1 * wy0, wx0 * wy1, wx1 * wy1};
        float wsum = 0.0f;
#pragma unroll
        for (int k = 0; k < 4; ++k) {
            const bool valid = (cx[k] >= 0.0f) && (cx[k] < (float)Ww) &&
                               (cy[k] >= 0.0f) && (cy[k] < (float)Hh);
            const float xc = fminf(fmaxf(cx[k], 0.0f), (float)(Ww - 1));
            const float yc = fminf(fmaxf(cy[k], 0.0f), (float)(Hh - 1));
            idxb[j][k] = ((int)yc * Ww + (int)xc) * Cc;
            wgt [j][k] = valid ? cw[k] : 0.0f;
            wsum += wgt[j][k];
        }
        vj[j] = wsum > 0.0f;
        anyv |= vj[j];
    }

    float* ob = out + ((size_t)b * Cc + cq * CPB) * (size_t)NPT + n0;

    if (!anyv) {
        // All 16 (j,k) weights zero -> output is exactly zero for all channels.
        const float4 z4 = make_float4(0.0f, 0.0f, 0.0f, 0.0f);
#pragma unroll
        for (int q = 0; q < CPB; ++q)
            *reinterpret_cast<float4*>(ob + (size_t)q * NPT) = z4;
        return;
    }

    const float* fb = featT + (size_t)b * HWc * Cc + cq * CPB;

#pragma unroll 2
    for (int cg = 0; cg < CPB / 4; ++cg) {
        float acc[4][4];   // [cc (channel within group)][j (z-step)]
#pragma unroll
        for (int cc = 0; cc < 4; ++cc)
#pragma unroll
            for (int j = 0; j < 4; ++j) acc[cc][j] = 0.0f;

#pragma unroll
        for (int j = 0; j < 4; ++j) {
            if (vj[j]) {
#pragma unroll
                for (int k = 0; k < 4; ++k) {
                    const float4 f = *reinterpret_cast<const float4*>(fb + idxb[j][k] + (cg << 2));
                    const float wk = wgt[j][k];
                    acc[0][j] = fmaf(wk, f.x, acc[0][j]);
                    acc[1][j] = fmaf(wk, f.y, acc[1][j]);
                    acc[2][j] = fmaf(wk, f.z, acc[2][j]);
                    acc[3][j] = fmaf(wk, f.w, acc[3][j]);
                }
            }
        }
#pragma unroll
        for (int cc = 0; cc < 4; ++cc) {
            *reinterpret_cast<float4*>(ob + (size_t)(cg * 4 + cc) * NPT) =
                make_float4(acc[cc][0], acc[cc][1], acc[cc][2], acc[cc][3]);
        }
    }
}

extern "C" void kernel_launch(void* const* d_in, const int* in_sizes, int n_in,
                              void* d_out, int out_size, void* d_ws, size_t ws_size,
                              hipStream_t stream) {
    const float* feat   = (const float*)d_in[0];
    const float* intrin = (const float*)d_in[1];
    const float* extrin = (const float*)d_in[2];
    const float* bda    = (const float*)d_in[3];
    float* out   = (float*)d_out;
    float* featT = (float*)d_ws;

    const int B = in_sizes[0] / (Cc * HWc);
    const int total = B * HWc * Cc;

    fvt_transpose<<<(total + 255) / 256, 256, 0, stream>>>(feat, featT, total);

    dim3 block(256);
    dim3 grid(NPT / 4 / 256, B, CSPLIT);
    fvt_kernel<<<grid, block, 0, stream>>>(featT, intrin, extrin, bda, out);
}

// Round 4
// 42.831 us; speedup vs baseline: 1.2056x; 1.0160x over previous
//
#include <hip/hip_runtime.h>
#include <hip/hip_bf16.h>

#define NXg 128
#define NYg 128
#define NZg 16
#define NPT (NXg * NYg * NZg)   // 262144
#define Hh 32
#define Ww 88
#define Cc 80
#define HWc (Hh * Ww)
#define CSPLIT 4
#define CPB (Cc / CSPLIT)       // 20 channels per block
#define NG (Cc / 4)             // 20 groups of 4 channels

// feat (B,C,H,W) -> featG (B, NG, H*W, 4)  : pixel stride 16B within a group
__global__ __launch_bounds__(256) void fvt_regroup(
    const float* __restrict__ feat, float* __restrict__ featG, int total)
{
    int t = blockIdx.x * 256 + threadIdx.x;
    if (t >= total) return;
    int cc = t & 3; int r = t >> 2;
    int p = r % HWc; r /= HWc;
    int g = r % NG;  int b = r / NG;
    featG[t] = feat[(((b * NG + g) * 4 + cc) * HWc) + p];
}

__global__ __launch_bounds__(256) void fvt_kernel(
    const float* __restrict__ featG,   // (B, NG, H*W, 4)
    const float* __restrict__ intrin,  // (B, 1, 4, 4)
    const float* __restrict__ extrin,  // (B, 1, 4, 4)
    const float* __restrict__ bda,     // (B, 4, 4)
    float* __restrict__ out)           // (B, C, NX, NY, NZ)
{
    const int b  = blockIdx.y;
    const int cq = blockIdx.z;
    const int t  = blockIdx.x * blockDim.x + threadIdx.x;
    const int n0 = t << 2;              // 4 consecutive n (same z-column)
    if (n0 >= NPT) return;

    const float* In = intrin + b * 16;
    const float* Ex = extrin + b * 16;
    const float* Bd = bda    + b * 16;

    float K[3][3];
#pragma unroll
    for (int r = 0; r < 3; ++r)
#pragma unroll
        for (int c = 0; c < 3; ++c)
            K[r][c] = In[r * 4 + c] * (r == 2 ? 1.0f : 0.125f);

    float P[3][4];
#pragma unroll
    for (int r = 0; r < 3; ++r)
#pragma unroll
        for (int c = 0; c < 4; ++c)
            P[r][c] = K[r][0] * Ex[0 * 4 + c] + K[r][1] * Ex[1 * 4 + c] + K[r][2] * Ex[2 * 4 + c];

    float M[3][4];
#pragma unroll
    for (int r = 0; r < 3; ++r)
#pragma unroll
        for (int c = 0; c < 4; ++c)
            M[r][c] = P[r][0] * Bd[0 * 4 + c] + P[r][1] * Bd[1 * 4 + c]
                    + P[r][2] * Bd[2 * 4 + c] + P[r][3] * Bd[3 * 4 + c];

    const int iz0 = n0 & (NZg - 1);
    const int iy  = (n0 >> 4) & (NYg - 1);
    const int ix  = n0 >> 11;
    const float xf = -51.2f + (float)ix * 0.8f;
    const float yf = -51.2f + (float)iy * 0.8f;

    int   idxb[4][4];   // [j (z-step)][k (corner)]  = pixel_index * 4 (float offset)
    float wgt [4][4];
    bool  vj  [4];
    bool  anyv = false;

#pragma unroll
    for (int j = 0; j < 4; ++j) {
        const float zf = -5.0f + (float)(iz0 + j) * 0.5f;

        const float px = M[0][0] * xf + M[0][1] * yf + M[0][2] * zf + M[0][3];
        const float py = M[1][0] * xf + M[1][1] * yf + M[1][2] * zf + M[1][3];
        const float pz = M[2][0] * xf + M[2][1] * yf + M[2][2] * zf + M[2][3];

        float u = px / pz;
        float v = py / pz;
        u = u / (float)Ww * 2.0f - 1.0f;
        v = v / (float)Hh * 2.0f - 1.0f;

        float x = (u + 1.0f) * 0.5f * (float)(Ww - 1);
        float y = (v + 1.0f) * 0.5f * (float)(Hh - 1);
        const bool fin = __builtin_isfinite(x) && __builtin_isfinite(y);
        x = fin ? x : -10.0f;
        y = fin ? y : -10.0f;

        const float x0 = floorf(x);
        const float y0 = floorf(y);
        const float x1 = x0 + 1.0f;
        const float y1 = y0 + 1.0f;
        const float wx1 = x - x0, wx0 = 1.0f - wx1;
        const float wy1 = y - y0, wy0 = 1.0f - wy1;

        const float cx[4] = {x0, x1, x0, x1};
        const float cy[4] = {y0, y0, y1, y1};
        const float cw[4] = {wx0 * wy0, wx1 * wy0, wx0 * wy1, wx1 * wy1};
        float wsum = 0.0f;
#pragma unroll
        for (int k = 0; k < 4; ++k) {
            const bool valid = (cx[k] >= 0.0f) && (cx[k] < (float)Ww) &&
                               (cy[k] >= 0.0f) && (cy[k] < (float)Hh);
            const float xc = fminf(fmaxf(cx[k], 0.0f), (float)(Ww - 1));
            const float yc = fminf(fmaxf(cy[k], 0.0f), (float)(Hh - 1));
            idxb[j][k] = ((int)yc * Ww + (int)xc) << 2;   // pixel * 4 floats
            wgt [j][k] = valid ? cw[k] : 0.0f;
            wsum += wgt[j][k];
        }
        vj[j] = wsum > 0.0f;
        anyv |= vj[j];
    }

    float* ob = out + ((size_t)b * Cc + cq * CPB) * (size_t)NPT + n0;

    if (!anyv) {
        const float4 z4 = make_float4(0.0f, 0.0f, 0.0f, 0.0f);
#pragma unroll
        for (int q = 0; q < CPB; ++q)
            *reinterpret_cast<float4*>(ob + (size_t)q * NPT) = z4;
        return;
    }

    // base group for this block: groups [cq*5, cq*5+5)
    const float* fb = featG + ((size_t)b * NG + cq * (CPB / 4)) * (size_t)(HWc * 4);

#pragma unroll 2
    for (int cg = 0; cg < CPB / 4; ++cg) {
        const float* fg = fb + (size_t)cg * (HWc * 4);
        float acc[4][4];   // [cc (channel within group)][j (z-step)]
#pragma unroll
        for (int cc = 0; cc < 4; ++cc)
#pragma unroll
            for (int j = 0; j < 4; ++j) acc[cc][j] = 0.0f;

#pragma unroll
        for (int j = 0; j < 4; ++j) {
            if (vj[j]) {
#pragma unroll
                for (int k = 0; k < 4; ++k) {
                    const float4 f = *reinterpret_cast<const float4*>(fg + idxb[j][k]);
                    const float wk = wgt[j][k];
                    acc[0][j] = fmaf(wk, f.x, acc[0][j]);
                    acc[1][j] = fmaf(wk, f.y, acc[1][j]);
                    acc[2][j] = fmaf(wk, f.z, acc[2][j]);
                    acc[3][j] = fmaf(wk, f.w, acc[3][j]);
                }
            }
        }
#pragma unroll
        for (int cc = 0; cc < 4; ++cc) {
            *reinterpret_cast<float4*>(ob + (size_t)(cg * 4 + cc) * NPT) =
                make_float4(acc[cc][0], acc[cc][1], acc[cc][2], acc[cc][3]);
        }
    }
}

extern "C" void kernel_launch(void* const* d_in, const int* in_sizes, int n_in,
                              void* d_out, int out_size, void* d_ws, size_t ws_size,
                              hipStream_t stream) {
    const float* feat   = (const float*)d_in[0];
    const float* intrin = (const float*)d_in[1];
    const float* extrin = (const float*)d_in[2];
    const float* bda    = (const float*)d_in[3];
    float* out   = (float*)d_out;
    float* featG = (float*)d_ws;

    const int B = in_sizes[0] / (Cc * HWc);
    const int total = B * Cc * HWc;   // == B * NG * HWc * 4

    fvt_regroup<<<(total + 255) / 256, 256, 0, stream>>>(feat, featG, total);

    dim3 block(256);
    dim3 grid(NPT / 4 / 256, B, CSPLIT);
    fvt_kernel<<<grid, block, 0, stream>>>(featG, intrin, extrin, bda, out);
}

// Round 5
// 41.050 us; speedup vs baseline: 1.2579x; 1.0434x over previous
//
#include <hip/hip_runtime.h>
#include <hip/hip_bf16.h>
#include <hip/hip_fp16.h>

#define NXg 128
#define NYg 128
#define NZg 16
#define NPT (NXg * NYg * NZg)   // 262144
#define Hh 32
#define Ww 88
#define Cc 80
#define HWc (Hh * Ww)
#define CSPLIT 4
#define CPB (Cc / CSPLIT)       // 20 channels per block
#define NG (Cc / 4)             // 20 groups of 4 channels

// feat (B,C,H,W) fp32 -> featH (B, NG, H*W, 4) fp16 : pixel stride 8B in a group
__global__ __launch_bounds__(256) void fvt_tohalf(
    const float* __restrict__ feat, unsigned short* __restrict__ featH, int total)
{
    int t = blockIdx.x * 256 + threadIdx.x;   // t = ((b*NG+g)*HWc + p)
    if (t >= total) return;
    int p = t % HWc; int r = t / HWc;
    int g = r % NG;  int b = r / NG;
    const float* src = feat + ((size_t)(b * Cc + g * 4)) * HWc + p;
    ushort4 px;
    px.x = __half_as_ushort(__float2half(src[0 * HWc]));
    px.y = __half_as_ushort(__float2half(src[1 * HWc]));
    px.z = __half_as_ushort(__float2half(src[2 * HWc]));
    px.w = __half_as_ushort(__float2half(src[3 * HWc]));
    *reinterpret_cast<ushort4*>(featH + (size_t)t * 4) = px;
}

union U2F2 { unsigned u; __half2 h; };
__device__ __forceinline__ float2 cvt2(unsigned u) {
    U2F2 c; c.u = u;
    return __half22float2(c.h);
}

__global__ __launch_bounds__(256) void fvt_kernel(
    const unsigned short* __restrict__ featH,  // (B, NG, H*W, 4) fp16
    const float* __restrict__ intrin,
    const float* __restrict__ extrin,
    const float* __restrict__ bda,
    float* __restrict__ out)                   // (B, C, NX, NY, NZ)
{
    const int b  = blockIdx.y;
    const int cq = blockIdx.z;
    const int t  = blockIdx.x * blockDim.x + threadIdx.x;
    const int n0 = t << 2;              // 4 consecutive n (same z-column)
    if (n0 >= NPT) return;

    const float* In = intrin + b * 16;
    const float* Ex = extrin + b * 16;
    const float* Bd = bda    + b * 16;

    float K[3][3];
#pragma unroll
    for (int r = 0; r < 3; ++r)
#pragma unroll
        for (int c = 0; c < 3; ++c)
            K[r][c] = In[r * 4 + c] * (r == 2 ? 1.0f : 0.125f);

    float P[3][4];
#pragma unroll
    for (int r = 0; r < 3; ++r)
#pragma unroll
        for (int c = 0; c < 4; ++c)
            P[r][c] = K[r][0] * Ex[0 * 4 + c] + K[r][1] * Ex[1 * 4 + c] + K[r][2] * Ex[2 * 4 + c];

    float M[3][4];
#pragma unroll
    for (int r = 0; r < 3; ++r)
#pragma unroll
        for (int c = 0; c < 4; ++c)
            M[r][c] = P[r][0] * Bd[0 * 4 + c] + P[r][1] * Bd[1 * 4 + c]
                    + P[r][2] * Bd[2 * 4 + c] + P[r][3] * Bd[3 * 4 + c];

    const int iz0 = n0 & (NZg - 1);
    const int iy  = (n0 >> 4) & (NYg - 1);
    const int ix  = n0 >> 11;
    const float xf = -51.2f + (float)ix * 0.8f;
    const float yf = -51.2f + (float)iy * 0.8f;

    int   off[4][2];    // [j][k: y0/y1]  halfword offset of the x-pair load
    float wlo[4][2];    // weight applied to lo pixel (xbase)
    float whi[4][2];    // weight applied to hi pixel (xbase+1)
    bool  vj [4];
    bool  anyv = false;

#pragma unroll
    for (int j = 0; j < 4; ++j) {
        const float zf = -5.0f + (float)(iz0 + j) * 0.5f;

        const float px = M[0][0] * xf + M[0][1] * yf + M[0][2] * zf + M[0][3];
        const float py = M[1][0] * xf + M[1][1] * yf + M[1][2] * zf + M[1][3];
        const float pz = M[2][0] * xf + M[2][1] * yf + M[2][2] * zf + M[2][3];

        float u = px / pz;
        float v = py / pz;
        u = u / (float)Ww * 2.0f - 1.0f;
        v = v / (float)Hh * 2.0f - 1.0f;

        float x = (u + 1.0f) * 0.5f * (float)(Ww - 1);
        float y = (v + 1.0f) * 0.5f * (float)(Hh - 1);
        const bool fin = __builtin_isfinite(x) && __builtin_isfinite(y);
        x = fin ? x : -10.0f;
        y = fin ? y : -10.0f;

        const float x0 = floorf(x);
        const float y0 = floorf(y);
        const float x1 = x0 + 1.0f;
        const float y1 = y0 + 1.0f;
        const float wx1 = x - x0, wx0 = 1.0f - wx1;
        const float wy1 = y - y0, wy0 = 1.0f - wy1;

        // per-corner masked weights (identical to reference semantics)
        const bool vx0 = (x0 >= 0.0f) && (x0 < (float)Ww);
        const bool vx1 = (x1 >= 0.0f) && (x1 < (float)Ww);
        const bool vy0 = (y0 >= 0.0f) && (y0 < (float)Hh);
        const bool vy1 = (y1 >= 0.0f) && (y1 < (float)Hh);
        const float w00 = (vx0 && vy0) ? wx0 * wy0 : 0.0f;
        const float w10 = (vx1 && vy0) ? wx1 * wy0 : 0.0f;
        const float w01 = (vx0 && vy1) ? wx0 * wy1 : 0.0f;
        const float w11 = (vx1 && vy1) ? wx1 * wy1 : 0.0f;

        const float xb  = fminf(fmaxf(x0, 0.0f), 86.0f);   // pair base
        const float y0c = fminf(fmaxf(y0, 0.0f), 31.0f);
        const float y1c = fminf(fmaxf(y1, 0.0f), 31.0f);

        const int xbi = (int)xb;
        off[0 * 0 + j][0] = ((int)y0c * Ww + xbi) * 4;
        off[j][1]         = ((int)y1c * Ww + xbi) * 4;

        // route corners to lo/hi slot of the pair (don't-cares have weight 0)
        const float lo_is_x0 = (x0 == xb) ? 1.0f : 0.0f;
        const float lo_is_x1 = (x1 == xb) ? 1.0f : 0.0f;
        const float hi_is_x0 = (x0 == xb + 1.0f) ? 1.0f : 0.0f;
        const float hi_is_x1 = (x1 == xb + 1.0f) ? 1.0f : 0.0f;
        wlo[j][0] = lo_is_x0 * w00 + lo_is_x1 * w10;
        whi[j][0] = hi_is_x0 * w00 + hi_is_x1 * w10;
        wlo[j][1] = lo_is_x0 * w01 + lo_is_x1 * w11;
        whi[j][1] = hi_is_x0 * w01 + hi_is_x1 * w11;

        const float wsum = w00 + w10 + w01 + w11;
        vj[j] = wsum > 0.0f;
        anyv |= vj[j];
    }

    float* ob = out + ((size_t)b * Cc + cq * CPB) * (size_t)NPT + n0;

    if (!anyv) {
        const float4 z4 = make_float4(0.0f, 0.0f, 0.0f, 0.0f);
#pragma unroll
        for (int q = 0; q < CPB; ++q)
            *reinterpret_cast<float4*>(ob + (size_t)q * NPT) = z4;
        return;
    }

    const unsigned short* fb = featH + ((size_t)b * NG + cq * (CPB / 4)) * (size_t)(HWc * 4);

#pragma unroll 2
    for (int cg = 0; cg < CPB / 4; ++cg) {
        const unsigned short* fg = fb + (size_t)cg * (HWc * 4);
        float acc[4][4];   // [cc][j]
#pragma unroll
        for (int cc = 0; cc < 4; ++cc)
#pragma unroll
            for (int j = 0; j < 4; ++j) acc[cc][j] = 0.0f;

#pragma unroll
        for (int j = 0; j < 4; ++j) {
            if (vj[j]) {
#pragma unroll
                for (int k = 0; k < 2; ++k) {
                    // 16B load = pixels (xb, xb+1) x 4 fp16 channels
                    const uint4 raw = *reinterpret_cast<const uint4*>(fg + off[j][k]);
                    const float wl = wlo[j][k];
                    const float wh = whi[j][k];
                    const float2 lo01 = cvt2(raw.x);
                    const float2 lo23 = cvt2(raw.y);
                    const float2 hi01 = cvt2(raw.z);
                    const float2 hi23 = cvt2(raw.w);
                    acc[0][j] = fmaf(wl, lo01.x, fmaf(wh, hi01.x, acc[0][j]));
                    acc[1][j] = fmaf(wl, lo01.y, fmaf(wh, hi01.y, acc[1][j]));
                    acc[2][j] = fmaf(wl, lo23.x, fmaf(wh, hi23.x, acc[2][j]));
                    acc[3][j] = fmaf(wl, lo23.y, fmaf(wh, hi23.y, acc[3][j]));
                }
            }
        }
#pragma unroll
        for (int cc = 0; cc < 4; ++cc) {
            *reinterpret_cast<float4*>(ob + (size_t)(cg * 4 + cc) * NPT) =
                make_float4(acc[cc][0], acc[cc][1], acc[cc][2], acc[cc][3]);
        }
    }
}

extern "C" void kernel_launch(void* const* d_in, const int* in_sizes, int n_in,
                              void* d_out, int out_size, void* d_ws, size_t ws_size,
                              hipStream_t stream) {
    const float* feat   = (const float*)d_in[0];
    const float* intrin = (const float*)d_in[1];
    const float* extrin = (const float*)d_in[2];
    const float* bda    = (const float*)d_in[3];
    float* out = (float*)d_out;
    unsigned short* featH = (unsigned short*)d_ws;

    const int B = in_sizes[0] / (Cc * HWc);
    const int total = B * NG * HWc;

    fvt_tohalf<<<(total + 255) / 256, 256, 0, stream>>>(feat, featH, total);

    dim3 block(256);
    dim3 grid(NPT / 4 / 256, B, CSPLIT);
    fvt_kernel<<<grid, block, 0, stream>>>(featH, intrin, extrin, bda, out);
}